// Round 1
// baseline (1817.387 us; speedup 1.0000x reference)
//
#include <hip/hip_runtime.h>
#include <hip/hip_bf16.h>
#include <stdint.h>

#define S 2048
#define D 64
#define H 4096
#define NB 8

typedef __bf16 bf16;
typedef __attribute__((ext_vector_type(8))) __bf16 bf16x8;
typedef __attribute__((ext_vector_type(4))) float f32x4;

__device__ __forceinline__ void load_lds16(const void* g, void* l) {
  __builtin_amdgcn_global_load_lds((const __attribute__((address_space(1))) void*)g,
                                   (__attribute__((address_space(3))) void*)l,
                                   16, 0, 0);
}

// ---------------------------------------------------------------------------
// Transpose + cast: W [K][N] f32  ->  Wt [N][K] bf16   (weights, once per call)
// ---------------------------------------------------------------------------
__global__ __launch_bounds__(256) void transpose_cast(const float* __restrict__ W,
                                                      bf16* __restrict__ Wt,
                                                      int K, int N) {
  __shared__ float tile[64][65];  // +1 pad: conflict-free transpose reads
  int k0 = blockIdx.y * 64, n0 = blockIdx.x * 64;
  int c = threadIdx.x & 63;
  int r4 = threadIdx.x >> 6;
#pragma unroll
  for (int i = 0; i < 16; ++i) {
    int r = i * 4 + r4;
    tile[r][c] = W[(size_t)(k0 + r) * N + n0 + c];
  }
  __syncthreads();
#pragma unroll
  for (int i = 0; i < 16; ++i) {
    int r = i * 4 + r4;  // n-local
    Wt[(size_t)(n0 + r) * K + k0 + c] = (bf16)tile[c][r];
  }
}

// ---------------------------------------------------------------------------
// scores[b,q,k] = dot(Q[b,q,:], K[b,k,:]) / 8   f32 compute -> bf16 out
// 64x64 tile per block, 256 threads, 4x4 outputs per thread
// ---------------------------------------------------------------------------
__global__ __launch_bounds__(256) void scores_k(const float* __restrict__ Q,
                                                const float* __restrict__ Km,
                                                bf16* __restrict__ Sc,
                                                long qkStride, long scStride) {
  int z = blockIdx.z;
  const float* Qb = Q + (size_t)z * qkStride;
  const float* Kb = Km + (size_t)z * qkStride;
  bf16* Scb = Sc + (size_t)z * scStride;
  __shared__ float Qs[64][65];
  __shared__ float Ks[64][65];
  int q0 = blockIdx.y * 64, k0 = blockIdx.x * 64;
  int c = threadIdx.x & 63, r4 = threadIdx.x >> 6;
#pragma unroll
  for (int i = 0; i < 16; ++i) {
    int r = i * 4 + r4;
    Qs[r][c] = Qb[(size_t)(q0 + r) * D + c];
    Ks[r][c] = Kb[(size_t)(k0 + r) * D + c];
  }
  __syncthreads();
  int tx = threadIdx.x & 15, ty = threadIdx.x >> 4;
  float acc[4][4] = {{0.f}};
  for (int d = 0; d < 64; ++d) {
    float a[4], b[4];
#pragma unroll
    for (int i = 0; i < 4; ++i) a[i] = Qs[ty * 4 + i][d];
#pragma unroll
    for (int j = 0; j < 4; ++j) b[j] = Ks[tx * 4 + j][d];
#pragma unroll
    for (int i = 0; i < 4; ++i)
#pragma unroll
      for (int j = 0; j < 4; ++j) acc[i][j] += a[i] * b[j];
  }
#pragma unroll
  for (int i = 0; i < 4; ++i)
#pragma unroll
    for (int j = 0; j < 4; ++j)
      Scb[(size_t)(q0 + ty * 4 + i) * S + (k0 + tx * 4 + j)] =
          (bf16)(acc[i][j] * 0.125f);
}

// ---------------------------------------------------------------------------
// GEMM: C[M][N] = epilogue(A[M][K] @ Bt[N][K]^T + bias[N])
// bf16 inputs, fp32 accum. 128x128 tile, BK=32, 256 threads (4 waves),
// each wave 64x64 via 4x4 of mfma_f32_16x16x32_bf16. global_load_lds width=16.
// ---------------------------------------------------------------------------
template <int RELU, int OUTBF16>
__global__ __launch_bounds__(256) void gemm_bt(const bf16* __restrict__ A,
                                               const bf16* __restrict__ Bt,
                                               const float* __restrict__ bias,
                                               void* __restrict__ Cv,
                                               int M, int N, int K,
                                               long strideA, long strideC) {
  __shared__ __align__(16) bf16 As[128 * 32];
  __shared__ __align__(16) bf16 Bs[128 * 32];
  int tid = threadIdx.x;
  int m0 = blockIdx.y * 128, n0 = blockIdx.x * 128;
  const bf16* Ab = A + (size_t)blockIdx.z * strideA;

  // staging: granule g (16B = 8 bf16) -> LDS offset g*8 elems; row = g>>2, kg = g&3
  int grow = tid >> 2;
  int gcol = (tid & 3) * 8;
  const bf16* gA0 = Ab + (size_t)(m0 + grow) * K + gcol;
  const bf16* gA1 = gA0 + (size_t)64 * K;
  const bf16* gB0 = Bt + (size_t)(n0 + grow) * K + gcol;
  const bf16* gB1 = gB0 + (size_t)64 * K;
  int w = tid >> 6;
  bf16* lA0 = As + w * 512;          // wave-uniform LDS base; HW adds lane*16B
  bf16* lA1 = As + 2048 + w * 512;
  bf16* lB0 = Bs + w * 512;
  bf16* lB1 = Bs + 2048 + w * 512;

  int lane = tid & 63;
  int mw = (w & 1) * 64, nw = (w >> 1) * 64;
  int lr = lane & 15;          // A: m-in-tile / B: n-in-tile
  int lk = (lane >> 4) * 8;    // k offset within BK
  const bf16* pa = As + (size_t)(mw + lr) * 32 + lk;
  const bf16* pb = Bs + (size_t)(nw + lr) * 32 + lk;

  f32x4 zero = {0.f, 0.f, 0.f, 0.f};
  f32x4 acc[4][4];
#pragma unroll
  for (int mt = 0; mt < 4; ++mt)
#pragma unroll
    for (int nt = 0; nt < 4; ++nt) acc[mt][nt] = zero;

  for (int k0 = 0; k0 < K; k0 += 32) {
    load_lds16(gA0, lA0);
    load_lds16(gA1, lA1);
    load_lds16(gB0, lB0);
    load_lds16(gB1, lB1);
    gA0 += 32; gA1 += 32; gB0 += 32; gB1 += 32;
    __syncthreads();
    bf16x8 af[4], bfr[4];
#pragma unroll
    for (int mt = 0; mt < 4; ++mt) af[mt] = *(const bf16x8*)(pa + mt * (16 * 32));
#pragma unroll
    for (int nt = 0; nt < 4; ++nt) bfr[nt] = *(const bf16x8*)(pb + nt * (16 * 32));
#pragma unroll
    for (int mt = 0; mt < 4; ++mt)
#pragma unroll
      for (int nt = 0; nt < 4; ++nt)
        acc[mt][nt] = __builtin_amdgcn_mfma_f32_16x16x32_bf16(af[mt], bfr[nt],
                                                              acc[mt][nt], 0, 0, 0);
    __syncthreads();
  }

  // epilogue; C/D layout: col = lane&15, row = (lane>>4)*4 + reg
  int mbase = m0 + mw + (lane >> 4) * 4;
  int nbase = n0 + nw + (lane & 15);
#pragma unroll
  for (int mt = 0; mt < 4; ++mt) {
#pragma unroll
    for (int nt = 0; nt < 4; ++nt) {
      int n = nbase + nt * 16;
      float bv = bias[n];
#pragma unroll
      for (int reg = 0; reg < 4; ++reg) {
        int m = mbase + mt * 16 + reg;
        float v = acc[mt][nt][reg] + bv;
        if (RELU) v = fmaxf(v, 0.f);
        if (OUTBF16) {
          bf16* C = (bf16*)Cv + (size_t)blockIdx.z * strideC;
          C[(size_t)m * N + n] = (bf16)v;
        } else {
          float* C = (float*)Cv + (size_t)blockIdx.z * strideC;
          C[(size_t)m * N + n] = v;
        }
      }
    }
  }
}

// ---------------------------------------------------------------------------
// Fused softmax (over k) + attn @ V.  4 q-rows per block, 256 threads.
// Phase 1: wave w = stats+exp for row w (stored unnormalized in LDS).
// Phase 2: wave w = k-range [w*512, w*512+512) for all 4 rows; LDS reduce.
// ---------------------------------------------------------------------------
__global__ __launch_bounds__(256) void softmax_av(const float* __restrict__ adj,
                                                  const float* __restrict__ V,
                                                  float* __restrict__ out,
                                                  long adjStride) {
  int z = blockIdx.y;
  const float* adjb = adj + (size_t)z * adjStride;
  const float* Vb = V + (size_t)z * (S * D);
  float* outb = out + (size_t)z * (S * D);
  int q0 = blockIdx.x * 4;
  __shared__ __align__(16) float attnL[4][S];
  __shared__ float red[4][4][64];
  __shared__ float rsum[4];
  int tid = threadIdx.x;
  int w = tid >> 6, lane = tid & 63;

  const float* rowp = adjb + (size_t)(q0 + w) * S;
  float lm = -1e30f;
  for (int k = 0; k < 32; ++k) lm = fmaxf(lm, rowp[lane + k * 64]);
#pragma unroll
  for (int off = 32; off > 0; off >>= 1) lm = fmaxf(lm, __shfl_xor(lm, off));
  float s = 0.f;
  for (int k = 0; k < 32; ++k) {
    float e = __expf(rowp[lane + k * 64] - lm);
    attnL[w][lane + k * 64] = e;
    s += e;
  }
#pragma unroll
  for (int off = 32; off > 0; off >>= 1) s += __shfl_xor(s, off);
  if (lane == 0) rsum[w] = s;
  __syncthreads();

  float acc0 = 0.f, acc1 = 0.f, acc2 = 0.f, acc3 = 0.f;
  int kbase = w * 512;
  for (int kk = 0; kk < 512; kk += 4) {
    int k = kbase + kk;
    float v0 = Vb[(size_t)(k + 0) * D + lane];
    float v1 = Vb[(size_t)(k + 1) * D + lane];
    float v2 = Vb[(size_t)(k + 2) * D + lane];
    float v3 = Vb[(size_t)(k + 3) * D + lane];
    f32x4 a0 = *(const f32x4*)&attnL[0][k];
    f32x4 a1 = *(const f32x4*)&attnL[1][k];
    f32x4 a2 = *(const f32x4*)&attnL[2][k];
    f32x4 a3 = *(const f32x4*)&attnL[3][k];
    acc0 += a0.x * v0 + a0.y * v1 + a0.z * v2 + a0.w * v3;
    acc1 += a1.x * v0 + a1.y * v1 + a1.z * v2 + a1.w * v3;
    acc2 += a2.x * v0 + a2.y * v1 + a2.z * v2 + a2.w * v3;
    acc3 += a3.x * v0 + a3.y * v1 + a3.z * v2 + a3.w * v3;
  }
  red[w][0][lane] = acc0;
  red[w][1][lane] = acc1;
  red[w][2][lane] = acc2;
  red[w][3][lane] = acc3;
  __syncthreads();
  int r = tid >> 6, d = tid & 63;
  float v = red[0][r][d] + red[1][r][d] + red[2][r][d] + red[3][r][d];
  outb[(size_t)(q0 + r) * D + d] = v / rsum[r];
}

// ---------------------------------------------------------------------------
extern "C" void kernel_launch(void* const* d_in, const int* in_sizes, int n_in,
                              void* d_out, int out_size, void* d_ws, size_t ws_size,
                              hipStream_t stream) {
  const float* Q  = (const float*)d_in[0];
  const float* Km = (const float*)d_in[1];
  const float* V  = (const float*)d_in[2];
  const float* W1 = (const float*)d_in[3];
  const float* b1 = (const float*)d_in[4];
  const float* W2 = (const float*)d_in[5];
  const float* b2 = (const float*)d_in[6];
  float* out = (float*)d_out;
  char* ws = (char*)d_ws;

  bf16* W1t = (bf16*)ws;                      // [H][S] bf16: 16 MB
  bf16* W2t = (bf16*)(ws + 16777216);         // [S][H] bf16: 16 MB
  transpose_cast<<<dim3(H / 64, S / 64), 256, 0, stream>>>(W1, W1t, S, H);
  transpose_cast<<<dim3(S / 64, H / 64), 256, 0, stream>>>(W2, W2t, H, S);

  if (ws_size >= 369098752ULL) {
    // full-batch path: 369 MB workspace, 6 launches total
    bf16* Sc   = (bf16*)(ws + 33554432);      // [B][S][S] bf16
    bf16* h    = (bf16*)(ws + 100663296);     // [B][S][H] bf16
    float* adj = (float*)(ws + 234881024);    // [B][S][S] f32
    scores_k<<<dim3(S / 64, S / 64, NB), 256, 0, stream>>>(Q, Km, Sc, (long)S * D,
                                                           (long)S * S);
    gemm_bt<1, 1><<<dim3(H / 128, S / 128, NB), 256, 0, stream>>>(
        Sc, W1t, b1, h, S, H, S, (long)S * S, (long)S * H);
    gemm_bt<0, 0><<<dim3(S / 128, S / 128, NB), 256, 0, stream>>>(
        h, W2t, b2, adj, S, S, H, (long)S * H, (long)S * S);
    softmax_av<<<dim3(S / 4, NB), 256, 0, stream>>>(adj, V, out, (long)S * S);
  } else {
    // per-batch path: 75 MB workspace, stream-serialized
    bf16* Sc   = (bf16*)(ws + 33554432);      // [S][S] bf16
    bf16* h    = (bf16*)(ws + 41943040);      // [S][H] bf16
    float* adj = (float*)(ws + 58720256);     // [S][S] f32
    for (int b = 0; b < NB; ++b) {
      scores_k<<<dim3(S / 64, S / 64, 1), 256, 0, stream>>>(
          Q + (size_t)b * S * D, Km + (size_t)b * S * D, Sc, 0, 0);
      gemm_bt<1, 1><<<dim3(H / 128, S / 128, 1), 256, 0, stream>>>(
          Sc, W1t, b1, h, S, H, S, 0, 0);
      gemm_bt<0, 0><<<dim3(S / 128, S / 128, 1), 256, 0, stream>>>(
          h, W2t, b2, adj, S, S, H, 0, 0);
      softmax_av<<<dim3(S / 4, 1), 256, 0, stream>>>(
          adj, V + (size_t)b * S * D, out + (size_t)b * S * D, 0);
    }
  }
}

// Round 2
// 1201.404 us; speedup vs baseline: 1.5127x; 1.5127x over previous
//
#include <hip/hip_runtime.h>
#include <hip/hip_bf16.h>
#include <stdint.h>

#define S 2048
#define D 64
#define H 4096
#define NB 8

typedef __bf16 bf16;
typedef __attribute__((ext_vector_type(8))) __bf16 bf16x8;
typedef __attribute__((ext_vector_type(4))) __bf16 bf16x4;
typedef __attribute__((ext_vector_type(4))) float f32x4;

__device__ __forceinline__ void load_lds16(const void* g, void* l) {
  __builtin_amdgcn_global_load_lds((const __attribute__((address_space(1))) void*)g,
                                   (__attribute__((address_space(3))) void*)l,
                                   16, 0, 0);
}

// ---------------------------------------------------------------------------
// Transpose + cast: W [K][N] f32  ->  Wt [N][K] bf16   (weights, once per call)
// ---------------------------------------------------------------------------
__global__ __launch_bounds__(256) void transpose_cast(const float* __restrict__ W,
                                                      bf16* __restrict__ Wt,
                                                      int K, int N) {
  __shared__ float tile[64][65];  // +1 pad: conflict-free transpose reads
  int k0 = blockIdx.y * 64, n0 = blockIdx.x * 64;
  int c = threadIdx.x & 63;
  int r4 = threadIdx.x >> 6;
#pragma unroll
  for (int i = 0; i < 16; ++i) {
    int r = i * 4 + r4;
    tile[r][c] = W[(size_t)(k0 + r) * N + n0 + c];
  }
  __syncthreads();
#pragma unroll
  for (int i = 0; i < 16; ++i) {
    int r = i * 4 + r4;  // n-local
    Wt[(size_t)(n0 + r) * K + k0 + c] = (bf16)tile[c][r];
  }
}

// ---------------------------------------------------------------------------
// scores[b,q,k] = dot(Q[b,q,:], K[b,k,:]) / 8   f32 compute -> bf16 out
// 64x64 tile per block, 256 threads, 4x4 outputs per thread
// ---------------------------------------------------------------------------
__global__ __launch_bounds__(256) void scores_k(const float* __restrict__ Q,
                                                const float* __restrict__ Km,
                                                bf16* __restrict__ Sc,
                                                long qkStride, long scStride) {
  int z = blockIdx.z;
  const float* Qb = Q + (size_t)z * qkStride;
  const float* Kb = Km + (size_t)z * qkStride;
  bf16* Scb = Sc + (size_t)z * scStride;
  __shared__ float Qs[64][65];
  __shared__ float Ks[64][65];
  int q0 = blockIdx.y * 64, k0 = blockIdx.x * 64;
  int c = threadIdx.x & 63, r4 = threadIdx.x >> 6;
#pragma unroll
  for (int i = 0; i < 16; ++i) {
    int r = i * 4 + r4;
    Qs[r][c] = Qb[(size_t)(q0 + r) * D + c];
    Ks[r][c] = Kb[(size_t)(k0 + r) * D + c];
  }
  __syncthreads();
  int tx = threadIdx.x & 15, ty = threadIdx.x >> 4;
  float acc[4][4] = {{0.f}};
  for (int d = 0; d < 64; ++d) {
    float a[4], b[4];
#pragma unroll
    for (int i = 0; i < 4; ++i) a[i] = Qs[ty * 4 + i][d];
#pragma unroll
    for (int j = 0; j < 4; ++j) b[j] = Ks[tx * 4 + j][d];
#pragma unroll
    for (int i = 0; i < 4; ++i)
#pragma unroll
      for (int j = 0; j < 4; ++j) acc[i][j] += a[i] * b[j];
  }
#pragma unroll
  for (int i = 0; i < 4; ++i) {
    bf16x4 pk;
#pragma unroll
    for (int j = 0; j < 4; ++j) pk[j] = (bf16)(acc[i][j] * 0.125f);
    *(bf16x4*)&Scb[(size_t)(q0 + ty * 4 + i) * S + (k0 + tx * 4)] = pk;
  }
}

// ---------------------------------------------------------------------------
// GEMM: C[M][N] = epilogue(A[M][K] @ Bt[N][K]^T + bias[N])
// bf16 inputs, fp32 accum. 128x128 tile, BK=32, 256 threads (4 waves),
// each wave 64x64 via 4x4 of mfma_f32_16x16x32_bf16. global_load_lds width=16.
// LDS layout XOR-swizzled: global k-chunk c of row r lives at LDS chunk
// c ^ ((r>>1)&3)  -> fragment ds_read_b128 addr16 pattern covers all 8
// 16B-slots exactly twice per 16-lane group = free 2-way (m136).
// ---------------------------------------------------------------------------
template <int RELU, int OUTBF16>
__global__ __launch_bounds__(256) void gemm_bt(const bf16* __restrict__ A,
                                               const bf16* __restrict__ Bt,
                                               const float* __restrict__ bias,
                                               void* __restrict__ Cv,
                                               int M, int N, int K,
                                               long strideA, long strideC) {
  __shared__ __align__(16) bf16 As[128 * 32];
  __shared__ __align__(16) bf16 Bs[128 * 32];
  int tid = threadIdx.x;
  int m0 = blockIdx.y * 128, n0 = blockIdx.x * 128;
  const bf16* Ab = A + (size_t)blockIdx.z * strideA;

  int lane = tid & 63;
  int w = tid >> 6;
  // staging: lane l of wave w covers row w*16 + (l>>2); its 16B granule lands
  // at LDS chunk l&3, so it must FETCH global chunk (l&3) ^ f(row),
  // f(row) = (row>>1)&3 = (l>>3)&3  (wave term w*8 vanishes mod 4).
  int grow = tid >> 2;
  int gcol = (((lane & 3) ^ ((lane >> 3) & 3)) * 8);
  const bf16* gA0 = Ab + (size_t)(m0 + grow) * K + gcol;
  const bf16* gA1 = gA0 + (size_t)64 * K;
  const bf16* gB0 = Bt + (size_t)(n0 + grow) * K + gcol;
  const bf16* gB1 = gB0 + (size_t)64 * K;
  bf16* lA0 = As + w * 512;          // wave-uniform LDS base; HW adds lane*16B
  bf16* lA1 = As + 2048 + w * 512;
  bf16* lB0 = Bs + w * 512;
  bf16* lB1 = Bs + 2048 + w * 512;

  int mw = (w & 1) * 64, nw = (w >> 1) * 64;
  int lr = lane & 15;          // A: m-in-tile / B: n-in-tile
  int ck = lane >> 4;          // k-chunk 0..3
  int swz = (ck ^ ((lr >> 1) & 3)) * 8;  // swizzled chunk offset (elems)
  const bf16* pa = As + (size_t)(mw + lr) * 32 + swz;
  const bf16* pb = Bs + (size_t)(nw + lr) * 32 + swz;

  f32x4 zero = {0.f, 0.f, 0.f, 0.f};
  f32x4 acc[4][4];
#pragma unroll
  for (int mt = 0; mt < 4; ++mt)
#pragma unroll
    for (int nt = 0; nt < 4; ++nt) acc[mt][nt] = zero;

  for (int k0 = 0; k0 < K; k0 += 32) {
    load_lds16(gA0, lA0);
    load_lds16(gA1, lA1);
    load_lds16(gB0, lB0);
    load_lds16(gB1, lB1);
    gA0 += 32; gA1 += 32; gB0 += 32; gB1 += 32;
    __syncthreads();
    bf16x8 af[4], bfr[4];
#pragma unroll
    for (int mt = 0; mt < 4; ++mt) af[mt] = *(const bf16x8*)(pa + mt * (16 * 32));
#pragma unroll
    for (int nt = 0; nt < 4; ++nt) bfr[nt] = *(const bf16x8*)(pb + nt * (16 * 32));
#pragma unroll
    for (int mt = 0; mt < 4; ++mt)
#pragma unroll
      for (int nt = 0; nt < 4; ++nt)
        acc[mt][nt] = __builtin_amdgcn_mfma_f32_16x16x32_bf16(af[mt], bfr[nt],
                                                              acc[mt][nt], 0, 0, 0);
    __syncthreads();
  }

  // epilogue; C/D layout: col = lane&15, row = (lane>>4)*4 + reg
  int mbase = m0 + mw + (lane >> 4) * 4;
  int nbase = n0 + nw + (lane & 15);
#pragma unroll
  for (int mt = 0; mt < 4; ++mt) {
#pragma unroll
    for (int nt = 0; nt < 4; ++nt) {
      int n = nbase + nt * 16;
      float bv = bias[n];
#pragma unroll
      for (int reg = 0; reg < 4; ++reg) {
        int m = mbase + mt * 16 + reg;
        float v = acc[mt][nt][reg] + bv;
        if (RELU) v = fmaxf(v, 0.f);
        if (OUTBF16) {
          bf16* C = (bf16*)Cv + (size_t)blockIdx.z * strideC;
          C[(size_t)m * N + n] = (bf16)v;
        } else {
          float* C = (float*)Cv + (size_t)blockIdx.z * strideC;
          C[(size_t)m * N + n] = v;
        }
      }
    }
  }
}

// ---------------------------------------------------------------------------
// Fused softmax (over k) + attn @ V.  4 q-rows per block, 256 threads.
// Phase 1: wave w = stats+exp for row w (stored unnormalized in LDS).
// Phase 2: wave w = k-range [w*512, w*512+512) for all 4 rows; LDS reduce.
// ---------------------------------------------------------------------------
__global__ __launch_bounds__(256) void softmax_av(const float* __restrict__ adj,
                                                  const float* __restrict__ V,
                                                  float* __restrict__ out,
                                                  long adjStride) {
  int z = blockIdx.y;
  const float* adjb = adj + (size_t)z * adjStride;
  const float* Vb = V + (size_t)z * (S * D);
  float* outb = out + (size_t)z * (S * D);
  int q0 = blockIdx.x * 4;
  __shared__ __align__(16) float attnL[4][S];
  __shared__ float red[4][4][64];
  __shared__ float rsum[4];
  int tid = threadIdx.x;
  int w = tid >> 6, lane = tid & 63;

  const float* rowp = adjb + (size_t)(q0 + w) * S;
  float lm = -1e30f;
  f32x4 rv[8];
#pragma unroll
  for (int k = 0; k < 8; ++k) {
    rv[k] = *(const f32x4*)&rowp[lane * 4 + k * 256];
    lm = fmaxf(fmaxf(fmaxf(rv[k].x, rv[k].y), fmaxf(rv[k].z, rv[k].w)), lm);
  }
#pragma unroll
  for (int off = 32; off > 0; off >>= 1) lm = fmaxf(lm, __shfl_xor(lm, off));
  float s = 0.f;
#pragma unroll
  for (int k = 0; k < 8; ++k) {
    f32x4 e;
    e.x = __expf(rv[k].x - lm);
    e.y = __expf(rv[k].y - lm);
    e.z = __expf(rv[k].z - lm);
    e.w = __expf(rv[k].w - lm);
    *(f32x4*)&attnL[w][lane * 4 + k * 256] = e;
    s += e.x + e.y + e.z + e.w;
  }
#pragma unroll
  for (int off = 32; off > 0; off >>= 1) s += __shfl_xor(s, off);
  if (lane == 0) rsum[w] = s;
  __syncthreads();

  float acc0 = 0.f, acc1 = 0.f, acc2 = 0.f, acc3 = 0.f;
  int kbase = w * 512;
  for (int kk = 0; kk < 512; kk += 4) {
    int k = kbase + kk;
    float v0 = Vb[(size_t)(k + 0) * D + lane];
    float v1 = Vb[(size_t)(k + 1) * D + lane];
    float v2 = Vb[(size_t)(k + 2) * D + lane];
    float v3 = Vb[(size_t)(k + 3) * D + lane];
    f32x4 a0 = *(const f32x4*)&attnL[0][k];
    f32x4 a1 = *(const f32x4*)&attnL[1][k];
    f32x4 a2 = *(const f32x4*)&attnL[2][k];
    f32x4 a3 = *(const f32x4*)&attnL[3][k];
    acc0 += a0.x * v0 + a0.y * v1 + a0.z * v2 + a0.w * v3;
    acc1 += a1.x * v0 + a1.y * v1 + a1.z * v2 + a1.w * v3;
    acc2 += a2.x * v0 + a2.y * v1 + a2.z * v2 + a2.w * v3;
    acc3 += a3.x * v0 + a3.y * v1 + a3.z * v2 + a3.w * v3;
  }
  red[w][0][lane] = acc0;
  red[w][1][lane] = acc1;
  red[w][2][lane] = acc2;
  red[w][3][lane] = acc3;
  __syncthreads();
  int r = tid >> 6, d = tid & 63;
  float v = red[0][r][d] + red[1][r][d] + red[2][r][d] + red[3][r][d];
  outb[(size_t)(q0 + r) * D + d] = v / rsum[r];
}

// ---------------------------------------------------------------------------
extern "C" void kernel_launch(void* const* d_in, const int* in_sizes, int n_in,
                              void* d_out, int out_size, void* d_ws, size_t ws_size,
                              hipStream_t stream) {
  const float* Q  = (const float*)d_in[0];
  const float* Km = (const float*)d_in[1];
  const float* V  = (const float*)d_in[2];
  const float* W1 = (const float*)d_in[3];
  const float* b1 = (const float*)d_in[4];
  const float* W2 = (const float*)d_in[5];
  const float* b2 = (const float*)d_in[6];
  float* out = (float*)d_out;
  char* ws = (char*)d_ws;

  bf16* W1t = (bf16*)ws;                      // [H][S] bf16: 16 MB
  bf16* W2t = (bf16*)(ws + 16777216);         // [S][H] bf16: 16 MB
  transpose_cast<<<dim3(H / 64, S / 64), 256, 0, stream>>>(W1, W1t, S, H);
  transpose_cast<<<dim3(S / 64, H / 64), 256, 0, stream>>>(W2, W2t, H, S);

  // group size G batches per kernel sequence: bytes = 32MB + G*40MB
  // (Sc bf16 G*8MB, h bf16 G*16MB, adj f32 G*16MB). R0 proved ws >= 75.5MB.
  int G = 1;
  if (ws_size >= 369098752ULL) G = 8;
  else if (ws_size >= 201326592ULL) G = 4;
  else if (ws_size >= 117440512ULL) G = 2;

  bf16* Sc   = (bf16*)(ws + 33554432);
  bf16* h    = (bf16*)(ws + 33554432 + (size_t)G * 8388608);
  float* adj = (float*)(ws + 33554432 + (size_t)G * 25165824);

  for (int b0 = 0; b0 < NB; b0 += G) {
    const float* Qb = Q + (size_t)b0 * S * D;
    const float* Kb = Km + (size_t)b0 * S * D;
    scores_k<<<dim3(S / 64, S / 64, G), 256, 0, stream>>>(Qb, Kb, Sc, (long)S * D,
                                                          (long)S * S);
    gemm_bt<1, 1><<<dim3(H / 128, S / 128, G), 256, 0, stream>>>(
        Sc, W1t, b1, h, S, H, S, (long)S * S, (long)S * H);
    gemm_bt<0, 0><<<dim3(S / 128, S / 128, G), 256, 0, stream>>>(
        h, W2t, b2, adj, S, S, H, (long)S * H, (long)S * S);
    softmax_av<<<dim3(S / 4, G), 256, 0, stream>>>(
        adj, V + (size_t)b0 * S * D, out + (size_t)b0 * S * D, (long)S * S);
  }
}

// Round 3
// 1174.929 us; speedup vs baseline: 1.5468x; 1.0225x over previous
//
#include <hip/hip_runtime.h>
#include <hip/hip_bf16.h>
#include <stdint.h>

#define S 2048
#define D 64
#define H 4096
#define NB 8

typedef __bf16 bf16;
typedef __attribute__((ext_vector_type(8))) __bf16 bf16x8;
typedef __attribute__((ext_vector_type(4))) __bf16 bf16x4;
typedef __attribute__((ext_vector_type(4))) float f32x4;

__device__ __forceinline__ void load_lds16(const void* g, void* l) {
  __builtin_amdgcn_global_load_lds((const __attribute__((address_space(1))) void*)g,
                                   (__attribute__((address_space(3))) void*)l,
                                   16, 0, 0);
}

// ---------------------------------------------------------------------------
// Transpose + cast: W [K][N] f32  ->  Wt [N][K] bf16   (weights, once per call)
// ---------------------------------------------------------------------------
__global__ __launch_bounds__(256) void transpose_cast(const float* __restrict__ W,
                                                      bf16* __restrict__ Wt,
                                                      int K, int N) {
  __shared__ float tile[64][65];
  int k0 = blockIdx.y * 64, n0 = blockIdx.x * 64;
  int c = threadIdx.x & 63;
  int r4 = threadIdx.x >> 6;
#pragma unroll
  for (int i = 0; i < 16; ++i) {
    int r = i * 4 + r4;
    tile[r][c] = W[(size_t)(k0 + r) * N + n0 + c];
  }
  __syncthreads();
#pragma unroll
  for (int i = 0; i < 16; ++i) {
    int r = i * 4 + r4;
    Wt[(size_t)(n0 + r) * K + k0 + c] = (bf16)tile[c][r];
  }
}

// ---------------------------------------------------------------------------
// scores[b,q,k] = dot(Q[b,q,:], K[b,k,:]) / 8   f32 compute -> bf16 out
// ---------------------------------------------------------------------------
__global__ __launch_bounds__(256) void scores_k(const float* __restrict__ Q,
                                                const float* __restrict__ Km,
                                                bf16* __restrict__ Sc,
                                                long qkStride, long scStride) {
  int z = blockIdx.z;
  const float* Qb = Q + (size_t)z * qkStride;
  const float* Kb = Km + (size_t)z * qkStride;
  bf16* Scb = Sc + (size_t)z * scStride;
  __shared__ float Qs[64][65];
  __shared__ float Ks[64][65];
  int q0 = blockIdx.y * 64, k0 = blockIdx.x * 64;
  int c = threadIdx.x & 63, r4 = threadIdx.x >> 6;
#pragma unroll
  for (int i = 0; i < 16; ++i) {
    int r = i * 4 + r4;
    Qs[r][c] = Qb[(size_t)(q0 + r) * D + c];
    Ks[r][c] = Kb[(size_t)(k0 + r) * D + c];
  }
  __syncthreads();
  int tx = threadIdx.x & 15, ty = threadIdx.x >> 4;
  float acc[4][4] = {{0.f}};
  for (int d = 0; d < 64; ++d) {
    float a[4], b[4];
#pragma unroll
    for (int i = 0; i < 4; ++i) a[i] = Qs[ty * 4 + i][d];
#pragma unroll
    for (int j = 0; j < 4; ++j) b[j] = Ks[tx * 4 + j][d];
#pragma unroll
    for (int i = 0; i < 4; ++i)
#pragma unroll
      for (int j = 0; j < 4; ++j) acc[i][j] += a[i] * b[j];
  }
#pragma unroll
  for (int i = 0; i < 4; ++i) {
    bf16x4 pk;
#pragma unroll
    for (int j = 0; j < 4; ++j) pk[j] = (bf16)(acc[i][j] * 0.125f);
    *(bf16x4*)&Scb[(size_t)(q0 + ty * 4 + i) * S + (k0 + tx * 4)] = pk;
  }
}

// ---------------------------------------------------------------------------
// GEMM: C[M][N] = epilogue(A[M][K] @ Bt[N][K]^T + bias[N])
// bf16 in, fp32 accum. 128x128 tile, BK=32, 4 waves.
// K-loop: depth-2 producer/consumer pipeline synchronized by LDS flags —
// NO s_barrier in the loop, so global_load_lds stays in flight across
// tile boundaries; drains are vmcnt(4), never vmcnt(0) (AITER/hipBLASLt
// style). flag[b] = #producer completions for buffer b (4 per round),
// done[b] = #consumer completions (buffer reusable when all 4 waves read it).
// LDS XOR-swizzle (R2, verified 0 bank conflicts) retained.
// ---------------------------------------------------------------------------
template <int RELU, int OUTBF16>
__global__ __launch_bounds__(256) void gemm_bt(const bf16* __restrict__ A,
                                               const bf16* __restrict__ Bt,
                                               const float* __restrict__ bias,
                                               void* __restrict__ Cv,
                                               int M, int N, int K,
                                               long strideA, long strideC) {
  __shared__ __align__(16) bf16 As[2][128 * 32];
  __shared__ __align__(16) bf16 Bs[2][128 * 32];
  __shared__ int flag[2];
  __shared__ int done[2];
  int tid = threadIdx.x;
  int lane = tid & 63;
  int w = tid >> 6;
  if (tid < 2) { flag[tid] = 0; done[tid] = 0; }
  __syncthreads();  // once, before the pipeline starts

  int m0 = blockIdx.y * 128, n0 = blockIdx.x * 128;
  const bf16* Ab = A + (size_t)blockIdx.z * strideA;

  // staging (swizzled fetch column; LDS dest = wave-uniform base + lane*16B)
  int grow = tid >> 2;
  int gcol = (((lane & 3) ^ ((lane >> 3) & 3)) * 8);
  const bf16* gA0 = Ab + (size_t)(m0 + grow) * K + gcol;
  const bf16* gA1 = gA0 + (size_t)64 * K;
  const bf16* gB0 = Bt + (size_t)(n0 + grow) * K + gcol;
  const bf16* gB1 = gB0 + (size_t)64 * K;
  int ldsOff = w * 512;

  int mw = (w & 1) * 64, nw = (w >> 1) * 64;
  int lr = lane & 15;
  int ck = lane >> 4;
  int swz = (ck ^ ((lr >> 1) & 3)) * 8;

  f32x4 zero = {0.f, 0.f, 0.f, 0.f};
  f32x4 acc[4][4];
#pragma unroll
  for (int mt = 0; mt < 4; ++mt)
#pragma unroll
    for (int nt = 0; nt < 4; ++nt) acc[mt][nt] = zero;

  const int niter = K / 32;  // >= 64 for all our shapes

#define STAGE(buf, koff)                                   \
  do {                                                     \
    load_lds16(gA0 + (koff), &As[buf][ldsOff]);            \
    load_lds16(gA1 + (koff), &As[buf][2048 + ldsOff]);     \
    load_lds16(gB0 + (koff), &Bs[buf][ldsOff]);            \
    load_lds16(gB1 + (koff), &Bs[buf][2048 + ldsOff]);     \
  } while (0)

  // prologue: tiles 0 and 1 in flight; publish tile 0
  STAGE(0, 0);
  STAGE(1, 32);
  asm volatile("s_waitcnt vmcnt(4)" ::: "memory");
  if (lane == 0)
    __hip_atomic_fetch_add(&flag[0], 1, __ATOMIC_RELEASE, __HIP_MEMORY_SCOPE_WORKGROUP);

  for (int it = 0; it < niter; ++it) {
    int b = it & 1;
    int tgt = 4 * ((it >> 1) + 1);
    // wait tile it ready
    while (__hip_atomic_load(&flag[b], __ATOMIC_ACQUIRE, __HIP_MEMORY_SCOPE_WORKGROUP) < tgt) {}
    // fragments
    const bf16* pa = &As[b][0] + (size_t)(mw + lr) * 32 + swz;
    const bf16* pb = &Bs[b][0] + (size_t)(nw + lr) * 32 + swz;
    bf16x8 af[4], bfr[4];
#pragma unroll
    for (int mt = 0; mt < 4; ++mt) af[mt] = *(const bf16x8*)(pa + mt * (16 * 32));
#pragma unroll
    for (int nt = 0; nt < 4; ++nt) bfr[nt] = *(const bf16x8*)(pb + nt * (16 * 32));
    // mark buffer consumed (ds ops are in-order per wave: add lands after reads)
    if (lane == 0)
      __hip_atomic_fetch_add(&done[b], 1, __ATOMIC_RELEASE, __HIP_MEMORY_SCOPE_WORKGROUP);
    // refill buffer b with tile it+2 once every wave has consumed tile it
    bool issued = (it + 2 < niter);
    if (issued) {
      while (__hip_atomic_load(&done[b], __ATOMIC_ACQUIRE, __HIP_MEMORY_SCOPE_WORKGROUP) < tgt) {}
      STAGE(b, (it + 2) * 32);
    }
#pragma unroll
    for (int mt = 0; mt < 4; ++mt)
#pragma unroll
      for (int nt = 0; nt < 4; ++nt)
        acc[mt][nt] = __builtin_amdgcn_mfma_f32_16x16x32_bf16(af[mt], bfr[nt],
                                                              acc[mt][nt], 0, 0, 0);
    // publish tile it+1 (its DMA was issued one full iteration ago)
    if (it + 1 < niter) {
      if (issued) asm volatile("s_waitcnt vmcnt(4)" ::: "memory");
      else        asm volatile("s_waitcnt vmcnt(0)" ::: "memory");
      if (lane == 0)
        __hip_atomic_fetch_add(&flag[(it + 1) & 1], 1, __ATOMIC_RELEASE,
                               __HIP_MEMORY_SCOPE_WORKGROUP);
    }
  }
#undef STAGE

  // epilogue; C/D layout: col = lane&15, row = (lane>>4)*4 + reg
  int mbase = m0 + mw + (lane >> 4) * 4;
  int nbase = n0 + nw + (lane & 15);
#pragma unroll
  for (int mt = 0; mt < 4; ++mt) {
#pragma unroll
    for (int nt = 0; nt < 4; ++nt) {
      int n = nbase + nt * 16;
      float bv = bias[n];
#pragma unroll
      for (int reg = 0; reg < 4; ++reg) {
        int m = mbase + mt * 16 + reg;
        float v = acc[mt][nt][reg] + bv;
        if (RELU) v = fmaxf(v, 0.f);
        if (OUTBF16) {
          bf16* C = (bf16*)Cv + (size_t)blockIdx.z * strideC;
          C[(size_t)m * N + n] = (bf16)v;
        } else {
          float* C = (float*)Cv + (size_t)blockIdx.z * strideC;
          C[(size_t)m * N + n] = v;
        }
      }
    }
  }
}

// ---------------------------------------------------------------------------
// Fused softmax (over k) + attn @ V.  4 q-rows per block, 256 threads.
// ---------------------------------------------------------------------------
__global__ __launch_bounds__(256) void softmax_av(const float* __restrict__ adj,
                                                  const float* __restrict__ V,
                                                  float* __restrict__ out,
                                                  long adjStride) {
  int z = blockIdx.y;
  const float* adjb = adj + (size_t)z * adjStride;
  const float* Vb = V + (size_t)z * (S * D);
  float* outb = out + (size_t)z * (S * D);
  int q0 = blockIdx.x * 4;
  __shared__ __align__(16) float attnL[4][S];
  __shared__ float red[4][4][64];
  __shared__ float rsum[4];
  int tid = threadIdx.x;
  int w = tid >> 6, lane = tid & 63;

  const float* rowp = adjb + (size_t)(q0 + w) * S;
  float lm = -1e30f;
  f32x4 rv[8];
#pragma unroll
  for (int k = 0; k < 8; ++k) {
    rv[k] = *(const f32x4*)&rowp[lane * 4 + k * 256];
    lm = fmaxf(fmaxf(fmaxf(rv[k].x, rv[k].y), fmaxf(rv[k].z, rv[k].w)), lm);
  }
#pragma unroll
  for (int off = 32; off > 0; off >>= 1) lm = fmaxf(lm, __shfl_xor(lm, off));
  float s = 0.f;
#pragma unroll
  for (int k = 0; k < 8; ++k) {
    f32x4 e;
    e.x = __expf(rv[k].x - lm);
    e.y = __expf(rv[k].y - lm);
    e.z = __expf(rv[k].z - lm);
    e.w = __expf(rv[k].w - lm);
    *(f32x4*)&attnL[w][lane * 4 + k * 256] = e;
    s += e.x + e.y + e.z + e.w;
  }
#pragma unroll
  for (int off = 32; off > 0; off >>= 1) s += __shfl_xor(s, off);
  if (lane == 0) rsum[w] = s;
  __syncthreads();

  float acc0 = 0.f, acc1 = 0.f, acc2 = 0.f, acc3 = 0.f;
  int kbase = w * 512;
  for (int kk = 0; kk < 512; kk += 4) {
    int k = kbase + kk;
    float v0 = Vb[(size_t)(k + 0) * D + lane];
    float v1 = Vb[(size_t)(k + 1) * D + lane];
    float v2 = Vb[(size_t)(k + 2) * D + lane];
    float v3 = Vb[(size_t)(k + 3) * D + lane];
    f32x4 a0 = *(const f32x4*)&attnL[0][k];
    f32x4 a1 = *(const f32x4*)&attnL[1][k];
    f32x4 a2 = *(const f32x4*)&attnL[2][k];
    f32x4 a3 = *(const f32x4*)&attnL[3][k];
    acc0 += a0.x * v0 + a0.y * v1 + a0.z * v2 + a0.w * v3;
    acc1 += a1.x * v0 + a1.y * v1 + a1.z * v2 + a1.w * v3;
    acc2 += a2.x * v0 + a2.y * v1 + a2.z * v2 + a2.w * v3;
    acc3 += a3.x * v0 + a3.y * v1 + a3.z * v2 + a3.w * v3;
  }
  red[w][0][lane] = acc0;
  red[w][1][lane] = acc1;
  red[w][2][lane] = acc2;
  red[w][3][lane] = acc3;
  __syncthreads();
  int r = tid >> 6, d = tid & 63;
  float v = red[0][r][d] + red[1][r][d] + red[2][r][d] + red[3][r][d];
  outb[(size_t)(q0 + r) * D + d] = v / rsum[r];
}

// ---------------------------------------------------------------------------
extern "C" void kernel_launch(void* const* d_in, const int* in_sizes, int n_in,
                              void* d_out, int out_size, void* d_ws, size_t ws_size,
                              hipStream_t stream) {
  const float* Q  = (const float*)d_in[0];
  const float* Km = (const float*)d_in[1];
  const float* V  = (const float*)d_in[2];
  const float* W1 = (const float*)d_in[3];
  const float* b1 = (const float*)d_in[4];
  const float* W2 = (const float*)d_in[5];
  const float* b2 = (const float*)d_in[6];
  float* out = (float*)d_out;
  char* ws = (char*)d_ws;

  bf16* W1t = (bf16*)ws;                      // [H][S] bf16: 16 MB
  bf16* W2t = (bf16*)(ws + 16777216);         // [S][H] bf16: 16 MB
  transpose_cast<<<dim3(H / 64, S / 64), 256, 0, stream>>>(W1, W1t, S, H);
  transpose_cast<<<dim3(S / 64, H / 64), 256, 0, stream>>>(W2, W2t, H, S);

  // group size G batches per kernel sequence: bytes = 32MB + G*40MB
  int G = 1;
  if (ws_size >= 369098752ULL) G = 8;
  else if (ws_size >= 201326592ULL) G = 4;
  else if (ws_size >= 117440512ULL) G = 2;

  bf16* Sc   = (bf16*)(ws + 33554432);
  bf16* h    = (bf16*)(ws + 33554432 + (size_t)G * 8388608);
  float* adj = (float*)(ws + 33554432 + (size_t)G * 25165824);

  for (int b0 = 0; b0 < NB; b0 += G) {
    const float* Qb = Q + (size_t)b0 * S * D;
    const float* Kb = Km + (size_t)b0 * S * D;
    scores_k<<<dim3(S / 64, S / 64, G), 256, 0, stream>>>(Qb, Kb, Sc, (long)S * D,
                                                          (long)S * S);
    gemm_bt<1, 1><<<dim3(H / 128, S / 128, G), 256, 0, stream>>>(
        Sc, W1t, b1, h, S, H, S, (long)S * S, (long)S * H);
    gemm_bt<0, 0><<<dim3(S / 128, S / 128, G), 256, 0, stream>>>(
        h, W2t, b2, adj, S, S, H, (long)S * H, (long)S * S);
    softmax_av<<<dim3(S / 4, G), 256, 0, stream>>>(
        adj, V + (size_t)b0 * S * D, out + (size_t)b0 * S * D, (long)S * S);
  }
}

// Round 5
// 1072.875 us; speedup vs baseline: 1.6939x; 1.0951x over previous
//
#include <hip/hip_runtime.h>
#include <hip/hip_bf16.h>
#include <stdint.h>

#define S 2048
#define D 64
#define H 4096
#define NB 8

typedef __bf16 bf16;
typedef __attribute__((ext_vector_type(8))) __bf16 bf16x8;
typedef __attribute__((ext_vector_type(4))) __bf16 bf16x4;
typedef __attribute__((ext_vector_type(4))) float f32x4;

// Raw LDS-DMA, invisible to the compiler's waitcnt pass (no auto vmcnt(0)).
// M0 = wave-uniform LDS byte offset; HW adds lane*16B.
// m0_bytes must be wave-uniform; readfirstlane forces it into an SGPR
// (uniformity analysis marks LDS-addrspacecast-derived values divergent,
// which made the bare "s" constraint fail to bind in R4).
__device__ __forceinline__ void dma16_raw(const bf16* g, uint32_t m0_bytes) {
  uint32_t m0s = __builtin_amdgcn_readfirstlane(m0_bytes);
  asm volatile("s_mov_b32 m0, %1\n\t"
               "global_load_lds_dwordx4 %0, off"
               :: "v"(g), "s"(m0s) : "memory");
}

__device__ __forceinline__ uint32_t lds_off_bytes(const void* p) {
  return (uint32_t)(uintptr_t)(__attribute__((address_space(3))) const void*)p;
}

// ---------------------------------------------------------------------------
// Transpose + cast: W [K][N] f32  ->  Wt [N][K] bf16   (weights, once per call)
// ---------------------------------------------------------------------------
__global__ __launch_bounds__(256) void transpose_cast(const float* __restrict__ W,
                                                      bf16* __restrict__ Wt,
                                                      int K, int N) {
  __shared__ float tile[64][65];
  int k0 = blockIdx.y * 64, n0 = blockIdx.x * 64;
  int c = threadIdx.x & 63;
  int r4 = threadIdx.x >> 6;
#pragma unroll
  for (int i = 0; i < 16; ++i) {
    int r = i * 4 + r4;
    tile[r][c] = W[(size_t)(k0 + r) * N + n0 + c];
  }
  __syncthreads();
#pragma unroll
  for (int i = 0; i < 16; ++i) {
    int r = i * 4 + r4;
    Wt[(size_t)(n0 + r) * K + k0 + c] = (bf16)tile[c][r];
  }
}

// ---------------------------------------------------------------------------
// scores[b,q,k] = dot(Q[b,q,:], K[b,k,:]) / 8   f32 compute -> bf16 out
// ---------------------------------------------------------------------------
__global__ __launch_bounds__(256) void scores_k(const float* __restrict__ Q,
                                                const float* __restrict__ Km,
                                                bf16* __restrict__ Sc,
                                                long qkStride, long scStride) {
  int z = blockIdx.z;
  const float* Qb = Q + (size_t)z * qkStride;
  const float* Kb = Km + (size_t)z * qkStride;
  bf16* Scb = Sc + (size_t)z * scStride;
  __shared__ float Qs[64][65];
  __shared__ float Ks[64][65];
  int q0 = blockIdx.y * 64, k0 = blockIdx.x * 64;
  int c = threadIdx.x & 63, r4 = threadIdx.x >> 6;
#pragma unroll
  for (int i = 0; i < 16; ++i) {
    int r = i * 4 + r4;
    Qs[r][c] = Qb[(size_t)(q0 + r) * D + c];
    Ks[r][c] = Kb[(size_t)(k0 + r) * D + c];
  }
  __syncthreads();
  int tx = threadIdx.x & 15, ty = threadIdx.x >> 4;
  float acc[4][4] = {{0.f}};
  for (int d = 0; d < 64; ++d) {
    float a[4], b[4];
#pragma unroll
    for (int i = 0; i < 4; ++i) a[i] = Qs[ty * 4 + i][d];
#pragma unroll
    for (int j = 0; j < 4; ++j) b[j] = Ks[tx * 4 + j][d];
#pragma unroll
    for (int i = 0; i < 4; ++i)
#pragma unroll
      for (int j = 0; j < 4; ++j) acc[i][j] += a[i] * b[j];
  }
#pragma unroll
  for (int i = 0; i < 4; ++i) {
    bf16x4 pk;
#pragma unroll
    for (int j = 0; j < 4; ++j) pk[j] = (bf16)(acc[i][j] * 0.125f);
    *(bf16x4*)&Scb[(size_t)(q0 + ty * 4 + i) * S + (k0 + tx * 4)] = pk;
  }
}

// ---------------------------------------------------------------------------
// GEMM: C[M][N] = epilogue(A[M][K] @ Bt[N][K]^T + bias[N])
// bf16 in, fp32 accum. 128x128 tile, BK=32, 4 waves.
// K-loop: double-buffered, depth-2 DMA prefetch with RAW-asm global_load_lds
// (untracked by the waitcnt pass) + raw s_barrier with hand-placed
// s_waitcnt vmcnt(4) — loads stay in flight across barriers (AITER-style).
// LDS XOR-swizzle (verified 0 bank conflicts) retained.
// ---------------------------------------------------------------------------
template <int RELU, int OUTBF16>
__global__ __launch_bounds__(256) void gemm_bt(const bf16* __restrict__ A,
                                               const bf16* __restrict__ Bt,
                                               const float* __restrict__ bias,
                                               void* __restrict__ Cv,
                                               int M, int N, int K,
                                               long strideA, long strideC) {
  // smem layout (bf16 elems): A buf0 [0,4096) | A buf1 [4096,8192)
  //                           B buf0 [8192,12288) | B buf1 [12288,16384)
  __shared__ __align__(16) bf16 smem[16384];
  int tid = threadIdx.x;
  int lane = tid & 63;
  int w = tid >> 6;

  int m0 = blockIdx.y * 128, n0 = blockIdx.x * 128;
  const bf16* Ab = A + (size_t)blockIdx.z * strideA;

  // staging: lane l of wave w covers row w*16 + (l>>2); granule lands at LDS
  // chunk l&3 -> fetch global chunk (l&3) ^ ((l>>3)&3)  (XOR swizzle).
  int grow = tid >> 2;
  int gcol = (((lane & 3) ^ ((lane >> 3) & 3)) * 8);
  const bf16* gA0 = Ab + (size_t)(m0 + grow) * K + gcol;
  const bf16* gA1 = gA0 + (size_t)64 * K;
  const bf16* gB0 = Bt + (size_t)(n0 + grow) * K + gcol;
  const bf16* gB1 = gB0 + (size_t)64 * K;

  // wave-uniform LDS byte offsets. Per buffer: A at buf*8192 B,
  // B at 16384 + buf*8192 B; wave section = w*1024 B; +4096 B for the
  // second 64-row half.
  uint32_t ldsBase = lds_off_bytes(&smem[0]);
  uint32_t wb = (uint32_t)(w * 1024);
  uint32_t mA[2], mB[2];
  mA[0] = ldsBase + wb;          mA[1] = ldsBase + 8192 + wb;
  mB[0] = ldsBase + 16384 + wb;  mB[1] = ldsBase + 24576 + wb;

  int mw = (w & 1) * 64, nw = (w >> 1) * 64;
  int lr = lane & 15;
  int ck = lane >> 4;
  int swz = (ck ^ ((lr >> 1) & 3)) * 8;
  const bf16* paBase = smem + (size_t)(mw + lr) * 32 + swz;         // + buf*4096
  const bf16* pbBase = smem + 8192 + (size_t)(nw + lr) * 32 + swz;  // + buf*4096

  f32x4 zero = {0.f, 0.f, 0.f, 0.f};
  f32x4 acc[4][4];
#pragma unroll
  for (int mt = 0; mt < 4; ++mt)
#pragma unroll
    for (int nt = 0; nt < 4; ++nt) acc[mt][nt] = zero;

  const int niter = K / 32;

#define STAGE(buf, koff)                                 \
  do {                                                   \
    dma16_raw(gA0 + (koff), mA[buf]);                    \
    dma16_raw(gA1 + (koff), mA[buf] + 4096);             \
    dma16_raw(gB0 + (koff), mB[buf]);                    \
    dma16_raw(gB1 + (koff), mB[buf] + 4096);             \
  } while (0)

  // prologue: tiles 0 and 1 in flight (8 outstanding per wave)
  STAGE(0, 0);
  STAGE(1, 32);

  for (int it = 0; it < niter; ++it) {
    int buf = it & 1;
    // tile `it` landed (own 4 oldest drained; rendezvous covers other waves).
    asm volatile("s_waitcnt vmcnt(4)\n\ts_barrier" ::: "memory");
    const bf16* pa = paBase + buf * 4096;
    const bf16* pb = pbBase + buf * 4096;
    bf16x8 af[4], bfr[4];
#pragma unroll
    for (int mt = 0; mt < 4; ++mt) af[mt] = *(const bf16x8*)(pa + mt * (16 * 32));
#pragma unroll
    for (int nt = 0; nt < 4; ++nt) bfr[nt] = *(const bf16x8*)(pb + nt * (16 * 32));
    // all waves finished reading `buf` -> safe to overwrite with tile it+2
    asm volatile("s_waitcnt lgkmcnt(0)\n\ts_barrier" ::: "memory");
    // keep 4-issues-per-iter invariant: tail iterations re-stage last tile
    int kpre = it + 2 < niter ? (it + 2) * 32 : (niter - 1) * 32;
    STAGE(buf, kpre);
#pragma unroll
    for (int mt = 0; mt < 4; ++mt)
#pragma unroll
      for (int nt = 0; nt < 4; ++nt)
        acc[mt][nt] = __builtin_amdgcn_mfma_f32_16x16x32_bf16(af[mt], bfr[nt],
                                                              acc[mt][nt], 0, 0, 0);
  }
#undef STAGE
  // drain leftover DMAs before LDS goes out of scope / epilogue
  asm volatile("s_waitcnt vmcnt(0)" ::: "memory");

  // epilogue; C/D layout: col = lane&15, row = (lane>>4)*4 + reg
  int mbase = m0 + mw + (lane >> 4) * 4;
  int nbase = n0 + nw + (lane & 15);
#pragma unroll
  for (int mt = 0; mt < 4; ++mt) {
#pragma unroll
    for (int nt = 0; nt < 4; ++nt) {
      int n = nbase + nt * 16;
      float bv = bias[n];
#pragma unroll
      for (int reg = 0; reg < 4; ++reg) {
        int m = mbase + mt * 16 + reg;
        float v = acc[mt][nt][reg] + bv;
        if (RELU) v = fmaxf(v, 0.f);
        if (OUTBF16) {
          bf16* C = (bf16*)Cv + (size_t)blockIdx.z * strideC;
          C[(size_t)m * N + n] = (bf16)v;
        } else {
          float* C = (float*)Cv + (size_t)blockIdx.z * strideC;
          C[(size_t)m * N + n] = v;
        }
      }
    }
  }
}

// ---------------------------------------------------------------------------
// Fused softmax (over k) + attn @ V.  4 q-rows per block, 256 threads.
// ---------------------------------------------------------------------------
__global__ __launch_bounds__(256) void softmax_av(const float* __restrict__ adj,
                                                  const float* __restrict__ V,
                                                  float* __restrict__ out,
                                                  long adjStride) {
  int z = blockIdx.y;
  const float* adjb = adj + (size_t)z * adjStride;
  const float* Vb = V + (size_t)z * (S * D);
  float* outb = out + (size_t)z * (S * D);
  int q0 = blockIdx.x * 4;
  __shared__ __align__(16) float attnL[4][S];
  __shared__ float red[4][4][64];
  __shared__ float rsum[4];
  int tid = threadIdx.x;
  int w = tid >> 6, lane = tid & 63;

  const float* rowp = adjb + (size_t)(q0 + w) * S;
  float lm = -1e30f;
  f32x4 rv[8];
#pragma unroll
  for (int k = 0; k < 8; ++k) {
    rv[k] = *(const f32x4*)&rowp[lane * 4 + k * 256];
    lm = fmaxf(fmaxf(fmaxf(rv[k].x, rv[k].y), fmaxf(rv[k].z, rv[k].w)), lm);
  }
#pragma unroll
  for (int off = 32; off > 0; off >>= 1) lm = fmaxf(lm, __shfl_xor(lm, off));
  float s = 0.f;
#pragma unroll
  for (int k = 0; k < 8; ++k) {
    f32x4 e;
    e.x = __expf(rv[k].x - lm);
    e.y = __expf(rv[k].y - lm);
    e.z = __expf(rv[k].z - lm);
    e.w = __expf(rv[k].w - lm);
    *(f32x4*)&attnL[w][lane * 4 + k * 256] = e;
    s += e.x + e.y + e.z + e.w;
  }
#pragma unroll
  for (int off = 32; off > 0; off >>= 1) s += __shfl_xor(s, off);
  if (lane == 0) rsum[w] = s;
  __syncthreads();

  float acc0 = 0.f, acc1 = 0.f, acc2 = 0.f, acc3 = 0.f;
  int kbase = w * 512;
  for (int kk = 0; kk < 512; kk += 4) {
    int k = kbase + kk;
    float v0 = Vb[(size_t)(k + 0) * D + lane];
    float v1 = Vb[(size_t)(k + 1) * D + lane];
    float v2 = Vb[(size_t)(k + 2) * D + lane];
    float v3 = Vb[(size_t)(k + 3) * D + lane];
    f32x4 a0 = *(const f32x4*)&attnL[0][k];
    f32x4 a1 = *(const f32x4*)&attnL[1][k];
    f32x4 a2 = *(const f32x4*)&attnL[2][k];
    f32x4 a3 = *(const f32x4*)&attnL[3][k];
    acc0 += a0.x * v0 + a0.y * v1 + a0.z * v2 + a0.w * v3;
    acc1 += a1.x * v0 + a1.y * v1 + a1.z * v2 + a1.w * v3;
    acc2 += a2.x * v0 + a2.y * v1 + a2.z * v2 + a2.w * v3;
    acc3 += a3.x * v0 + a3.y * v1 + a3.z * v2 + a3.w * v3;
  }
  red[w][0][lane] = acc0;
  red[w][1][lane] = acc1;
  red[w][2][lane] = acc2;
  red[w][3][lane] = acc3;
  __syncthreads();
  int r = tid >> 6, d = tid & 63;
  float v = red[0][r][d] + red[1][r][d] + red[2][r][d] + red[3][r][d];
  outb[(size_t)(q0 + r) * D + d] = v / rsum[r];
}

// ---------------------------------------------------------------------------
extern "C" void kernel_launch(void* const* d_in, const int* in_sizes, int n_in,
                              void* d_out, int out_size, void* d_ws, size_t ws_size,
                              hipStream_t stream) {
  const float* Q  = (const float*)d_in[0];
  const float* Km = (const float*)d_in[1];
  const float* V  = (const float*)d_in[2];
  const float* W1 = (const float*)d_in[3];
  const float* b1 = (const float*)d_in[4];
  const float* W2 = (const float*)d_in[5];
  const float* b2 = (const float*)d_in[6];
  float* out = (float*)d_out;
  char* ws = (char*)d_ws;

  bf16* W1t = (bf16*)ws;                      // [H][S] bf16: 16 MB
  bf16* W2t = (bf16*)(ws + 16777216);         // [S][H] bf16: 16 MB
  transpose_cast<<<dim3(H / 64, S / 64), 256, 0, stream>>>(W1, W1t, S, H);
  transpose_cast<<<dim3(S / 64, H / 64), 256, 0, stream>>>(W2, W2t, H, S);

  // group size G batches per kernel sequence: bytes = 32MB + G*40MB
  int G = 1;
  if (ws_size >= 369098752ULL) G = 8;
  else if (ws_size >= 201326592ULL) G = 4;
  else if (ws_size >= 117440512ULL) G = 2;

  bf16* Sc   = (bf16*)(ws + 33554432);
  bf16* h    = (bf16*)(ws + 33554432 + (size_t)G * 8388608);
  float* adj = (float*)(ws + 33554432 + (size_t)G * 25165824);

  for (int b0 = 0; b0 < NB; b0 += G) {
    const float* Qb = Q + (size_t)b0 * S * D;
    const float* Kb = Km + (size_t)b0 * S * D;
    scores_k<<<dim3(S / 64, S / 64, G), 256, 0, stream>>>(Qb, Kb, Sc, (long)S * D,
                                                          (long)S * S);
    gemm_bt<1, 1><<<dim3(H / 128, S / 128, G), 256, 0, stream>>>(
        Sc, W1t, b1, h, S, H, S, (long)S * S, (long)S * H);
    gemm_bt<0, 0><<<dim3(S / 128, S / 128, G), 256, 0, stream>>>(
        h, W2t, b2, adj, S, S, H, (long)S * H, (long)S * S);
    softmax_av<<<dim3(S / 4, G), 256, 0, stream>>>(
        adj, V + (size_t)b0 * S * D, out + (size_t)b0 * S * D, (long)S * S);
  }
}

// Round 6
// 1060.317 us; speedup vs baseline: 1.7140x; 1.0118x over previous
//
#include <hip/hip_runtime.h>
#include <hip/hip_bf16.h>
#include <stdint.h>

#define S 2048
#define D 64
#define H 4096
#define NB 8

typedef __bf16 bf16;
typedef __attribute__((ext_vector_type(8))) __bf16 bf16x8;
typedef __attribute__((ext_vector_type(4))) __bf16 bf16x4;
typedef __attribute__((ext_vector_type(4))) float f32x4;

// Raw LDS-DMA, invisible to the compiler's waitcnt pass (no auto vmcnt(0)).
// M0 = wave-uniform LDS byte offset; HW adds lane*16B.
__device__ __forceinline__ void dma16_raw(const bf16* g, uint32_t m0_bytes) {
  uint32_t m0s = __builtin_amdgcn_readfirstlane(m0_bytes);
  asm volatile("s_mov_b32 m0, %1\n\t"
               "global_load_lds_dwordx4 %0, off"
               :: "v"(g), "s"(m0s) : "memory");
}

__device__ __forceinline__ uint32_t lds_off_bytes(const void* p) {
  return (uint32_t)(uintptr_t)(__attribute__((address_space(3))) const void*)p;
}

// ---------------------------------------------------------------------------
// Transpose + cast: W [K][N] f32  ->  Wt [N][K] bf16   (weights, once per call)
// ---------------------------------------------------------------------------
__global__ __launch_bounds__(256) void transpose_cast(const float* __restrict__ W,
                                                      bf16* __restrict__ Wt,
                                                      int K, int N) {
  __shared__ float tile[64][65];
  int k0 = blockIdx.y * 64, n0 = blockIdx.x * 64;
  int c = threadIdx.x & 63;
  int r4 = threadIdx.x >> 6;
#pragma unroll
  for (int i = 0; i < 16; ++i) {
    int r = i * 4 + r4;
    tile[r][c] = W[(size_t)(k0 + r) * N + n0 + c];
  }
  __syncthreads();
#pragma unroll
  for (int i = 0; i < 16; ++i) {
    int r = i * 4 + r4;
    Wt[(size_t)(n0 + r) * K + k0 + c] = (bf16)tile[c][r];
  }
}

// ---------------------------------------------------------------------------
// scores[b,q,k] = dot(Q[b,q,:], K[b,k,:]) / 8   f32 compute -> bf16 out
// ---------------------------------------------------------------------------
__global__ __launch_bounds__(256) void scores_k(const float* __restrict__ Q,
                                                const float* __restrict__ Km,
                                                bf16* __restrict__ Sc,
                                                long qkStride, long scStride) {
  int z = blockIdx.z;
  const float* Qb = Q + (size_t)z * qkStride;
  const float* Kb = Km + (size_t)z * qkStride;
  bf16* Scb = Sc + (size_t)z * scStride;
  __shared__ float Qs[64][65];
  __shared__ float Ks[64][65];
  int q0 = blockIdx.y * 64, k0 = blockIdx.x * 64;
  int c = threadIdx.x & 63, r4 = threadIdx.x >> 6;
#pragma unroll
  for (int i = 0; i < 16; ++i) {
    int r = i * 4 + r4;
    Qs[r][c] = Qb[(size_t)(q0 + r) * D + c];
    Ks[r][c] = Kb[(size_t)(k0 + r) * D + c];
  }
  __syncthreads();
  int tx = threadIdx.x & 15, ty = threadIdx.x >> 4;
  float acc[4][4] = {{0.f}};
  for (int d = 0; d < 64; ++d) {
    float a[4], b[4];
#pragma unroll
    for (int i = 0; i < 4; ++i) a[i] = Qs[ty * 4 + i][d];
#pragma unroll
    for (int j = 0; j < 4; ++j) b[j] = Ks[tx * 4 + j][d];
#pragma unroll
    for (int i = 0; i < 4; ++i)
#pragma unroll
      for (int j = 0; j < 4; ++j) acc[i][j] += a[i] * b[j];
  }
#pragma unroll
  for (int i = 0; i < 4; ++i) {
    bf16x4 pk;
#pragma unroll
    for (int j = 0; j < 4; ++j) pk[j] = (bf16)(acc[i][j] * 0.125f);
    *(bf16x4*)&Scb[(size_t)(q0 + ty * 4 + i) * S + (k0 + tx * 4)] = pk;
  }
}

// ---------------------------------------------------------------------------
// GEMM: C[M][N] = epilogue(A[M][K] @ Bt[N][K]^T + bias[N])
// bf16 in, fp32 accum. 128x128 tile, BK=32, 4 waves.
// K-loop: 3-buffer rotation, ONE barrier per K-step. At iter `it`:
//   barrier (vmcnt(4): tile it landed; lgkmcnt(0): everyone's reads of the
//   iter it-1 buffer done) -> DMA tile it+2 into buf (it+2)%3 (== the buffer
//   read at iter it-1) -> ds_read frags from buf it%3 -> 16 MFMA.
// DMA slack = 2 iterations (covers ~900cyc HBM-miss latency). Raw-asm DMA
// stays invisible to the compiler's waitcnt pass (R5-verified).
// LDS XOR-swizzle (verified 0 bank conflicts) retained.
// ---------------------------------------------------------------------------
template <int RELU, int OUTBF16>
__global__ __launch_bounds__(256, 3) void gemm_bt(const bf16* __restrict__ A,
                                                  const bf16* __restrict__ Bt,
                                                  const float* __restrict__ bias,
                                                  void* __restrict__ Cv,
                                                  int M, int N, int K,
                                                  long strideA, long strideC) {
  // smem (bf16 elems): A bufs at b*4096, b=0..2; B bufs at 12288 + b*4096.
  __shared__ __align__(16) bf16 smem[24576];  // 48 KB
  int tid = threadIdx.x;
  int lane = tid & 63;
  int w = tid >> 6;

  int m0 = blockIdx.y * 128, n0 = blockIdx.x * 128;
  const bf16* Ab = A + (size_t)blockIdx.z * strideA;

  // staging: lane l of wave w covers row w*16 + (l>>2); granule lands at LDS
  // chunk l&3 -> fetch global chunk (l&3) ^ ((l>>3)&3)  (XOR swizzle).
  int grow = tid >> 2;
  int gcol = (((lane & 3) ^ ((lane >> 3) & 3)) * 8);
  const bf16* gA0 = Ab + (size_t)(m0 + grow) * K + gcol;
  const bf16* gA1 = gA0 + (size_t)64 * K;
  const bf16* gB0 = Bt + (size_t)(n0 + grow) * K + gcol;
  const bf16* gB1 = gB0 + (size_t)64 * K;

  // wave-uniform LDS byte offsets. A buf b at b*8192 B; B at 24576 + b*8192 B;
  // wave section w*1024 B; +4096 B for second 64-row half.
  uint32_t ldsBase = lds_off_bytes(&smem[0]);
  uint32_t wb = (uint32_t)(w * 1024);
  uint32_t mA[3], mB[3];
#pragma unroll
  for (int b = 0; b < 3; ++b) {
    mA[b] = ldsBase + b * 8192 + wb;
    mB[b] = ldsBase + 24576 + b * 8192 + wb;
  }

  int mw = (w & 1) * 64, nw = (w >> 1) * 64;
  int lr = lane & 15;
  int ck = lane >> 4;
  int swz = (ck ^ ((lr >> 1) & 3)) * 8;
  const bf16* paBase = smem + (size_t)(mw + lr) * 32 + swz;          // + buf*4096
  const bf16* pbBase = smem + 12288 + (size_t)(nw + lr) * 32 + swz;  // + buf*4096

  f32x4 zero = {0.f, 0.f, 0.f, 0.f};
  f32x4 acc[4][4];
#pragma unroll
  for (int mt = 0; mt < 4; ++mt)
#pragma unroll
    for (int nt = 0; nt < 4; ++nt) acc[mt][nt] = zero;

  const int niter = K / 32;

#define STAGE(buf, koff)                                 \
  do {                                                   \
    dma16_raw(gA0 + (koff), mA[buf]);                    \
    dma16_raw(gA1 + (koff), mA[buf] + 4096);             \
    dma16_raw(gB0 + (koff), mB[buf]);                    \
    dma16_raw(gB1 + (koff), mB[buf] + 4096);             \
  } while (0)

  // prologue: tiles 0 and 1 in flight (8 outstanding per wave)
  STAGE(0, 0);
  STAGE(1, 32);

  int buf = 0;          // it % 3
  int pbuf = 2;         // (it+2) % 3
  for (int it = 0; it < niter; ++it) {
    // tile `it` landed; all waves' reads of the iter it-1 buffer are done.
    asm volatile("s_waitcnt vmcnt(4) lgkmcnt(0)\n\ts_barrier" ::: "memory");
    // prefetch tile it+2 into buf (it+2)%3 (tail: re-stage last tile to keep
    // the 4-issues-per-iter vmcnt invariant; never read again, harmless)
    int kpre = it + 2 < niter ? (it + 2) * 32 : (niter - 1) * 32;
    STAGE(pbuf, kpre);
    const bf16* pa = paBase + buf * 4096;
    const bf16* pb = pbBase + buf * 4096;
    bf16x8 af[4], bfr[4];
#pragma unroll
    for (int mt = 0; mt < 4; ++mt) af[mt] = *(const bf16x8*)(pa + mt * (16 * 32));
#pragma unroll
    for (int nt = 0; nt < 4; ++nt) bfr[nt] = *(const bf16x8*)(pb + nt * (16 * 32));
#pragma unroll
    for (int mt = 0; mt < 4; ++mt)
#pragma unroll
      for (int nt = 0; nt < 4; ++nt)
        acc[mt][nt] = __builtin_amdgcn_mfma_f32_16x16x32_bf16(af[mt], bfr[nt],
                                                              acc[mt][nt], 0, 0, 0);
    buf = buf == 2 ? 0 : buf + 1;
    pbuf = pbuf == 2 ? 0 : pbuf + 1;
  }
#undef STAGE
  // drain leftover DMAs before LDS is reused by the next block
  asm volatile("s_waitcnt vmcnt(0)" ::: "memory");

  // epilogue; C/D layout: col = lane&15, row = (lane>>4)*4 + reg
  int mbase = m0 + mw + (lane >> 4) * 4;
  int nbase = n0 + nw + (lane & 15);
#pragma unroll
  for (int mt = 0; mt < 4; ++mt) {
#pragma unroll
    for (int nt = 0; nt < 4; ++nt) {
      int n = nbase + nt * 16;
      float bv = bias[n];
#pragma unroll
      for (int reg = 0; reg < 4; ++reg) {
        int m = mbase + mt * 16 + reg;
        float v = acc[mt][nt][reg] + bv;
        if (RELU) v = fmaxf(v, 0.f);
        if (OUTBF16) {
          bf16* C = (bf16*)Cv + (size_t)blockIdx.z * strideC;
          C[(size_t)m * N + n] = (bf16)v;
        } else {
          float* C = (float*)Cv + (size_t)blockIdx.z * strideC;
          C[(size_t)m * N + n] = v;
        }
      }
    }
  }
}

// ---------------------------------------------------------------------------
// Fused softmax (over k) + attn @ V.  4 q-rows per block, 256 threads.
// ---------------------------------------------------------------------------
__global__ __launch_bounds__(256) void softmax_av(const float* __restrict__ adj,
                                                  const float* __restrict__ V,
                                                  float* __restrict__ out,
                                                  long adjStride) {
  int z = blockIdx.y;
  const float* adjb = adj + (size_t)z * adjStride;
  const float* Vb = V + (size_t)z * (S * D);
  float* outb = out + (size_t)z * (S * D);
  int q0 = blockIdx.x * 4;
  __shared__ __align__(16) float attnL[4][S];
  __shared__ float red[4][4][64];
  __shared__ float rsum[4];
  int tid = threadIdx.x;
  int w = tid >> 6, lane = tid & 63;

  const float* rowp = adjb + (size_t)(q0 + w) * S;
  float lm = -1e30f;
  f32x4 rv[8];
#pragma unroll
  for (int k = 0; k < 8; ++k) {
    rv[k] = *(const f32x4*)&rowp[lane * 4 + k * 256];
    lm = fmaxf(fmaxf(fmaxf(rv[k].x, rv[k].y), fmaxf(rv[k].z, rv[k].w)), lm);
  }
#pragma unroll
  for (int off = 32; off > 0; off >>= 1) lm = fmaxf(lm, __shfl_xor(lm, off));
  float s = 0.f;
#pragma unroll
  for (int k = 0; k < 8; ++k) {
    f32x4 e;
    e.x = __expf(rv[k].x - lm);
    e.y = __expf(rv[k].y - lm);
    e.z = __expf(rv[k].z - lm);
    e.w = __expf(rv[k].w - lm);
    *(f32x4*)&attnL[w][lane * 4 + k * 256] = e;
    s += e.x + e.y + e.z + e.w;
  }
#pragma unroll
  for (int off = 32; off > 0; off >>= 1) s += __shfl_xor(s, off);
  if (lane == 0) rsum[w] = s;
  __syncthreads();

  float acc0 = 0.f, acc1 = 0.f, acc2 = 0.f, acc3 = 0.f;
  int kbase = w * 512;
  for (int kk = 0; kk < 512; kk += 4) {
    int k = kbase + kk;
    float v0 = Vb[(size_t)(k + 0) * D + lane];
    float v1 = Vb[(size_t)(k + 1) * D + lane];
    float v2 = Vb[(size_t)(k + 2) * D + lane];
    float v3 = Vb[(size_t)(k + 3) * D + lane];
    f32x4 a0 = *(const f32x4*)&attnL[0][k];
    f32x4 a1 = *(const f32x4*)&attnL[1][k];
    f32x4 a2 = *(const f32x4*)&attnL[2][k];
    f32x4 a3 = *(const f32x4*)&attnL[3][k];
    acc0 += a0.x * v0 + a0.y * v1 + a0.z * v2 + a0.w * v3;
    acc1 += a1.x * v0 + a1.y * v1 + a1.z * v2 + a1.w * v3;
    acc2 += a2.x * v0 + a2.y * v1 + a2.z * v2 + a2.w * v3;
    acc3 += a3.x * v0 + a3.y * v1 + a3.z * v2 + a3.w * v3;
  }
  red[w][0][lane] = acc0;
  red[w][1][lane] = acc1;
  red[w][2][lane] = acc2;
  red[w][3][lane] = acc3;
  __syncthreads();
  int r = tid >> 6, d = tid & 63;
  float v = red[0][r][d] + red[1][r][d] + red[2][r][d] + red[3][r][d];
  outb[(size_t)(q0 + r) * D + d] = v / rsum[r];
}

// ---------------------------------------------------------------------------
extern "C" void kernel_launch(void* const* d_in, const int* in_sizes, int n_in,
                              void* d_out, int out_size, void* d_ws, size_t ws_size,
                              hipStream_t stream) {
  const float* Q  = (const float*)d_in[0];
  const float* Km = (const float*)d_in[1];
  const float* V  = (const float*)d_in[2];
  const float* W1 = (const float*)d_in[3];
  const float* b1 = (const float*)d_in[4];
  const float* W2 = (const float*)d_in[5];
  const float* b2 = (const float*)d_in[6];
  float* out = (float*)d_out;
  char* ws = (char*)d_ws;

  bf16* W1t = (bf16*)ws;                      // [H][S] bf16: 16 MB
  bf16* W2t = (bf16*)(ws + 16777216);         // [S][H] bf16: 16 MB
  transpose_cast<<<dim3(H / 64, S / 64), 256, 0, stream>>>(W1, W1t, S, H);
  transpose_cast<<<dim3(S / 64, H / 64), 256, 0, stream>>>(W2, W2t, H, S);

  // Aliased layout: [weights 32MB][X: G*16MB][h: G*16MB].
  // Sc (bf16, G*8MB) and adj (f32, G*16MB) both live in X: Sc is dead once
  // gemm1 completes, and gemm2 (writer of adj) runs strictly after it.
  // footprint = 32MB + G*32MB. R2 proved ws in [192MiB, 352MiB).
  int G = 1;
  if (ws_size >= 301989888ULL) G = 8;        // 288 MiB
  else if (ws_size >= 167772160ULL) G = 4;   // 160 MiB
  else if (ws_size >= 100663296ULL) G = 2;   //  96 MiB

  bf16* Sc   = (bf16*)(ws + 33554432);
  float* adj = (float*)(ws + 33554432);
  bf16* h    = (bf16*)(ws + 33554432 + (size_t)G * 16777216);

  for (int b0 = 0; b0 < NB; b0 += G) {
    const float* Qb = Q + (size_t)b0 * S * D;
    const float* Kb = Km + (size_t)b0 * S * D;
    scores_k<<<dim3(S / 64, S / 64, G), 256, 0, stream>>>(Qb, Kb, Sc, (long)S * D,
                                                          (long)S * S);
    gemm_bt<1, 1><<<dim3(H / 128, S / 128, G), 256, 0, stream>>>(
        Sc, W1t, b1, h, S, H, S, (long)S * S, (long)S * H);
    gemm_bt<0, 0><<<dim3(S / 128, S / 128, G), 256, 0, stream>>>(
        h, W2t, b2, adj, S, S, H, (long)S * H, (long)S * S);
    softmax_av<<<dim3(S / 4, G), 256, 0, stream>>>(
        adj, V + (size_t)b0 * S * D, out + (size_t)b0 * S * D, (long)S * S);
  }
}